// Round 10
// baseline (161.275 us; speedup 1.0000x reference)
//
#include <hip/hip_runtime.h>
#include <hip/hip_cooperative_groups.h>

namespace cg = cooperative_groups;

// UpsampleFlow2: Gaussian Nadaraya-Watson upsampling.
// out [B,3,N] = (sum_s k*f)/(sum_s k), k = exp(-|x-y|^2/r^2).
// exp(-|x|^2/r^2) cancels in num/den ->
//   k' = exp2( fma(px,ax, fma(py,ay, fma(pz,az, bias))) )
//   a = c2*y, bias = cy*|y|^2, c2=2*log2e/r^2, cy=-log2e/r^2.
//
// R10: SINGLE COOPERATIVE DISPATCH. Budget fit across R5-R9:
//   31.25us (R8) = inner 13.9 + partial traffic 2.5 + ~15us fixed "A".
// A is not VALU (R9 pk null) nor LDS (0 conflicts) -> dispatch overhead,
// combine launch + gap, tail. Fuse combine into the main kernel behind
// grid.sync(): one launch, partials stay L2/L3-warm.
// Phase 1: R5-proven scalar inner, PPT=8, CHUNK=64, SC=32 -> 512 blocks
// (2 blocks/CU, co-resident for coop). Phase 2: first BN threads reduce
// SC partials + normalize + write.

constexpr int B_ = 4, N_ = 8192, S_ = 2048;
constexpr int BLOCK = 256, PPT = 8, SC = 32;
constexpr int PTS_PER_BLOCK = BLOCK * PPT;      // 2048
constexpr int NBPB = N_ / PTS_PER_BLOCK;        // 4
constexpr int NB = B_ * NBPB;                   // 16
constexpr int CHUNK = S_ / SC;                  // 64
constexpr int BN = B_ * N_;                     // 32768
constexpr float LOG2E = 1.4426950408889634f;

__global__ __launch_bounds__(BLOCK, 2) void uf2_coop(
    const float* __restrict__ xyz,
    const float* __restrict__ sxyz,
    const float* __restrict__ sflow,
    const int* __restrict__ resol,
    float4* __restrict__ part,
    float* __restrict__ out)
{
    __shared__ float4 As[CHUNK];   // (c2*yx, c2*yy, c2*yz, cy*|y|^2)
    __shared__ float4 Fs[CHUNK];   // (fx, fy, fz, unused)

    const int nb = blockIdx.x % NB;
    const int sc = blockIdx.x / NB;
    const int b  = nb / NBPB;
    const int n0 = (nb % NBPB) * PTS_PER_BLOCK;
    const int s0 = sc * CHUNK;

    const float r = (float)resol[0];            // INITIAL_RADIUS(=1)*resol
    const float inv_r2 = 1.0f / (r * r);
    const float c2 = 2.0f * inv_r2 * LOG2E;
    const float cy = -inv_r2 * LOG2E;

    // ---- phase 1: stage + pack sparse chunk into LDS ----
    const float* yb = sxyz  + b * 3 * S_;
    const float* fb = sflow + b * 3 * S_;
    for (int t = threadIdx.x; t < CHUNK; t += BLOCK) {
        const int s = s0 + t;
        const float yx = yb[s], yy = yb[S_ + s], yz = yb[2 * S_ + s];
        const float fx = fb[s], fy = fb[S_ + s], fz = fb[2 * S_ + s];
        As[t] = make_float4(c2 * yx, c2 * yy, c2 * yz,
                            cy * (yx * yx + yy * yy + yz * yz));
        Fs[t] = make_float4(fx, fy, fz, 0.0f);
    }
    __syncthreads();

    const float* xb = xyz + b * 3 * N_;
    float px[PPT], py[PPT], pz[PPT];
    float ax[PPT], ay[PPT], az[PPT], aw[PPT];
#pragma unroll
    for (int p = 0; p < PPT; ++p) {
        const int n = n0 + threadIdx.x + p * BLOCK;
        px[p] = xb[n]; py[p] = xb[N_ + n]; pz[p] = xb[2 * N_ + n];
        ax[p] = 0.f; ay[p] = 0.f; az[p] = 0.f; aw[p] = 0.f;
    }

#pragma unroll 2
    for (int t = 0; t < CHUNK; ++t) {
        const float4 a = As[t];   // broadcast ds_read_b128
        const float4 f = Fs[t];
#pragma unroll
        for (int p = 0; p < PPT; ++p) {
            float e = fmaf(pz[p], a.z, a.w);
            e = fmaf(py[p], a.y, e);
            e = fmaf(px[p], a.x, e);
            const float k = __builtin_amdgcn_exp2f(e);
            ax[p] = fmaf(k, f.x, ax[p]);
            ay[p] = fmaf(k, f.y, ay[p]);
            az[p] = fmaf(k, f.z, az[p]);
            aw[p] += k;
        }
    }

#pragma unroll
    for (int p = 0; p < PPT; ++p) {
        const int g = b * N_ + n0 + threadIdx.x + p * BLOCK;
        part[(size_t)sc * BN + g] = make_float4(ax[p], ay[p], az[p], aw[p]);
    }

    // ---- grid-wide barrier (device-scope visibility for partials) ----
    __threadfence();
    cg::this_grid().sync();

    // ---- phase 2: first BN threads reduce + normalize + write ----
    const int g = blockIdx.x * BLOCK + threadIdx.x;
    if (g < BN) {
        float4 s0v = make_float4(0.f, 0.f, 0.f, 0.f);
        float4 s1v = s0v, s2v = s0v, s3v = s0v;
#pragma unroll
        for (int c = 0; c < SC; c += 4) {
            const float4 p0 = part[(size_t)(c + 0) * BN + g];
            const float4 p1 = part[(size_t)(c + 1) * BN + g];
            const float4 p2 = part[(size_t)(c + 2) * BN + g];
            const float4 p3 = part[(size_t)(c + 3) * BN + g];
            s0v.x += p0.x; s0v.y += p0.y; s0v.z += p0.z; s0v.w += p0.w;
            s1v.x += p1.x; s1v.y += p1.y; s1v.z += p1.z; s1v.w += p1.w;
            s2v.x += p2.x; s2v.y += p2.y; s2v.z += p2.z; s2v.w += p2.w;
            s3v.x += p3.x; s3v.y += p3.y; s3v.z += p3.z; s3v.w += p3.w;
        }
        const float sx = (s0v.x + s1v.x) + (s2v.x + s3v.x);
        const float sy = (s0v.y + s1v.y) + (s2v.y + s3v.y);
        const float sz = (s0v.z + s1v.z) + (s2v.z + s3v.z);
        const float sw = (s0v.w + s1v.w) + (s2v.w + s3v.w);
        const float inv = 1.0f / sw;
        const int ob_ = g >> 13;          // /8192
        const int n = g & (N_ - 1);
        float* ob = out + ob_ * 3 * N_;
        ob[n]          = sx * inv;
        ob[N_ + n]     = sy * inv;
        ob[2 * N_ + n] = sz * inv;
    }
}

// ---------- fallback two-dispatch path (R8 structure) ----------
template <int FCHUNK>
__global__ __launch_bounds__(BLOCK, 4) void uf2_main(
    const float* __restrict__ xyz,
    const float* __restrict__ sxyz,
    const float* __restrict__ sflow,
    const int* __restrict__ resol,
    float4* __restrict__ part)
{
    __shared__ float4 As[FCHUNK];
    __shared__ float4 Fs[FCHUNK];

    const int nb = blockIdx.x % NB;
    const int sc = blockIdx.x / NB;
    const int b  = nb / NBPB;
    const int n0 = (nb % NBPB) * PTS_PER_BLOCK;
    const int s0 = sc * FCHUNK;

    const float r = (float)resol[0];
    const float inv_r2 = 1.0f / (r * r);
    const float c2 = 2.0f * inv_r2 * LOG2E;
    const float cy = -inv_r2 * LOG2E;

    const float* yb = sxyz  + b * 3 * S_;
    const float* fb = sflow + b * 3 * S_;
    for (int t = threadIdx.x; t < FCHUNK; t += BLOCK) {
        const int s = s0 + t;
        const float yx = yb[s], yy = yb[S_ + s], yz = yb[2 * S_ + s];
        const float fx = fb[s], fy = fb[S_ + s], fz = fb[2 * S_ + s];
        As[t] = make_float4(c2 * yx, c2 * yy, c2 * yz,
                            cy * (yx * yx + yy * yy + yz * yz));
        Fs[t] = make_float4(fx, fy, fz, 0.0f);
    }
    __syncthreads();

    const float* xb = xyz + b * 3 * N_;
    float px[PPT], py[PPT], pz[PPT];
    float ax[PPT], ay[PPT], az[PPT], aw[PPT];
#pragma unroll
    for (int p = 0; p < PPT; ++p) {
        const int n = n0 + threadIdx.x + p * BLOCK;
        px[p] = xb[n]; py[p] = xb[N_ + n]; pz[p] = xb[2 * N_ + n];
        ax[p] = 0.f; ay[p] = 0.f; az[p] = 0.f; aw[p] = 0.f;
    }
#pragma unroll 2
    for (int t = 0; t < FCHUNK; ++t) {
        const float4 a = As[t];
        const float4 f = Fs[t];
#pragma unroll
        for (int p = 0; p < PPT; ++p) {
            float e = fmaf(pz[p], a.z, a.w);
            e = fmaf(py[p], a.y, e);
            e = fmaf(px[p], a.x, e);
            const float k = __builtin_amdgcn_exp2f(e);
            ax[p] = fmaf(k, f.x, ax[p]);
            ay[p] = fmaf(k, f.y, ay[p]);
            az[p] = fmaf(k, f.z, az[p]);
            aw[p] += k;
        }
    }
#pragma unroll
    for (int p = 0; p < PPT; ++p) {
        const int g = b * N_ + n0 + threadIdx.x + p * BLOCK;
        part[(size_t)sc * BN + g] = make_float4(ax[p], ay[p], az[p], aw[p]);
    }
}

__global__ __launch_bounds__(BLOCK) void uf2_combine(
    const float4* __restrict__ part, float* __restrict__ out, int nsc)
{
    const int g = blockIdx.x * BLOCK + threadIdx.x;
    float4 s0 = make_float4(0.f, 0.f, 0.f, 0.f);
    float4 s1 = s0, s2 = s0, s3 = s0;
    int c = 0;
    for (; c + 4 <= nsc; c += 4) {
        const float4 p0 = part[(size_t)(c + 0) * BN + g];
        const float4 p1 = part[(size_t)(c + 1) * BN + g];
        const float4 p2 = part[(size_t)(c + 2) * BN + g];
        const float4 p3 = part[(size_t)(c + 3) * BN + g];
        s0.x += p0.x; s0.y += p0.y; s0.z += p0.z; s0.w += p0.w;
        s1.x += p1.x; s1.y += p1.y; s1.z += p1.z; s1.w += p1.w;
        s2.x += p2.x; s2.y += p2.y; s2.z += p2.z; s2.w += p2.w;
        s3.x += p3.x; s3.y += p3.y; s3.z += p3.z; s3.w += p3.w;
    }
    for (; c < nsc; ++c) {
        const float4 p = part[(size_t)c * BN + g];
        s0.x += p.x; s0.y += p.y; s0.z += p.z; s0.w += p.w;
    }
    const float sx = (s0.x + s1.x) + (s2.x + s3.x);
    const float sy = (s0.y + s1.y) + (s2.y + s3.y);
    const float sz = (s0.z + s1.z) + (s2.z + s3.z);
    const float sw = (s0.w + s1.w) + (s2.w + s3.w);
    const float inv = 1.0f / sw;
    const int b = g >> 13;
    const int n = g & (N_ - 1);
    float* ob = out + b * 3 * N_;
    ob[n]          = sx * inv;
    ob[N_ + n]     = sy * inv;
    ob[2 * N_ + n] = sz * inv;
}

extern "C" void kernel_launch(void* const* d_in, const int* in_sizes, int n_in,
                              void* d_out, int out_size, void* d_ws, size_t ws_size,
                              hipStream_t stream)
{
    const float* xyz   = (const float*)d_in[0];
    const float* sxyz  = (const float*)d_in[1];
    const float* sflow = (const float*)d_in[2];
    const int*   resol = (const int*)d_in[3];
    float* out   = (float*)d_out;
    float4* part = (float4*)d_ws;

    const size_t need = (size_t)SC * BN * sizeof(float4);   // 16 MB

    if (need <= ws_size) {
        void* args[] = {(void*)&xyz, (void*)&sxyz, (void*)&sflow,
                        (void*)&resol, (void*)&part, (void*)&out};
        hipError_t err = hipLaunchCooperativeKernel(
            (const void*)uf2_coop, dim3(NB * SC), dim3(BLOCK), args, 0, stream);
        if (err == hipSuccess) return;
        // else fall through to two-dispatch path
    }

    // fallback: two-dispatch R8 path (SC=16)
    const size_t per_chunk = (size_t)BN * sizeof(float4);
    int nsc = 16;
    while (nsc > 1 && (size_t)nsc * per_chunk > ws_size) nsc >>= 1;

    dim3 grid(NB * nsc), blk(BLOCK);
    switch (nsc) {
        case 16: uf2_main<S_ / 16><<<grid, blk, 0, stream>>>(xyz, sxyz, sflow, resol, part); break;
        case 8:  uf2_main<S_ / 8 ><<<grid, blk, 0, stream>>>(xyz, sxyz, sflow, resol, part); break;
        case 4:  uf2_main<S_ / 4 ><<<grid, blk, 0, stream>>>(xyz, sxyz, sflow, resol, part); break;
        case 2:  uf2_main<S_ / 2 ><<<grid, blk, 0, stream>>>(xyz, sxyz, sflow, resol, part); break;
        default: uf2_main<S_     ><<<grid, blk, 0, stream>>>(xyz, sxyz, sflow, resol, part); break;
    }
    uf2_combine<<<dim3(BN / BLOCK), dim3(BLOCK), 0, stream>>>(part, out, nsc);
}

// Round 11
// 48.353 us; speedup vs baseline: 3.3354x; 3.3354x over previous
//
#include <hip/hip_runtime.h>

// UpsampleFlow2: Gaussian Nadaraya-Watson upsampling.
// out [B,3,N] = (sum_s k*f)/(sum_s k), k = exp(-|x-y|^2/r^2).
// exp(-|x|^2/r^2) cancels in num/den ->
//   k' = exp2( fma(px,ax, fma(py,ay, fma(pz,az, bias))) )
//   a = c2*y, bias = cy*|y|^2, c2=2*log2e/r^2, cy=-log2e/r^2.
//
// R11: DECOMPOSITION ROUND on the R8 structure (best: 31.25us).
// REPS=2 wraps the ENTIRE body (query loads + LDS staging + inner +
// partial writes), with per-rep pointer laundering (incl. part, so rep-1
// stores are not dead-store-eliminated and rep-1 compute survives DCE).
// Output unchanged (idempotent re-writes). Algebra:
//   body = R11_total - 31.25 ; K = main_row - 2*body ; L = total - row.
// R5 already pinned steady-state inner = 13.9us -> prologue/write/ramp
// portion = body - 13.9. Coop (R10) is dead: grid.sync() ~ 115us.

constexpr int B_ = 4, N_ = 8192, S_ = 2048;
constexpr int BLOCK = 256, PPT = 8, REPS = 2;
constexpr int PTS_PER_BLOCK = BLOCK * PPT;      // 2048
constexpr int NBPB = N_ / PTS_PER_BLOCK;        // 4
constexpr int NB = B_ * NBPB;                   // 16
constexpr int BN = B_ * N_;                     // 32768
constexpr float LOG2E = 1.4426950408889634f;

template <int CHUNK>
__global__ __launch_bounds__(BLOCK, 4) void uf2_main(
    const float* __restrict__ xyz,
    const float* __restrict__ sxyz,
    const float* __restrict__ sflow,
    const int* __restrict__ resol,
    float4* __restrict__ part)
{
    __shared__ float4 As[CHUNK];   // (c2*yx, c2*yy, c2*yz, cy*|y|^2)
    __shared__ float4 Fs[CHUNK];   // (fx, fy, fz, unused)

    const int nb = blockIdx.x % NB;
    const int sc = blockIdx.x / NB;
    const int b  = nb / NBPB;
    const int n0 = (nb % NBPB) * PTS_PER_BLOCK;
    const int s0 = sc * CHUNK;

    const float r = (float)resol[0];            // INITIAL_RADIUS(=1)*resol
    const float inv_r2 = 1.0f / (r * r);
    const float c2 = 2.0f * inv_r2 * LOG2E;
    const float cy = -inv_r2 * LOG2E;

    const float* yb0 = sxyz  + b * 3 * S_;
    const float* fb0 = sflow + b * 3 * S_;
    const float* xb0 = xyz   + b * 3 * N_;

#pragma unroll 1
    for (int rep = 0; rep < REPS; ++rep) {
        // launder all bases: rep bodies can't be CSE'd/DCE'd across reps
        const float* yb = yb0;
        const float* fb = fb0;
        const float* xb = xb0;
        float4* pp = part;
        asm volatile("" : "+v"(yb), "+v"(fb), "+v"(xb), "+v"(pp));

        // ---- stage + pack sparse chunk into LDS ----
        for (int t = threadIdx.x; t < CHUNK; t += BLOCK) {
            const int s = s0 + t;
            const float yx = yb[s], yy = yb[S_ + s], yz = yb[2 * S_ + s];
            const float fx = fb[s], fy = fb[S_ + s], fz = fb[2 * S_ + s];
            As[t] = make_float4(c2 * yx, c2 * yy, c2 * yz,
                                cy * (yx * yx + yy * yy + yz * yz));
            Fs[t] = make_float4(fx, fy, fz, 0.0f);
        }
        __syncthreads();

        // ---- per-thread query points ----
        float px[PPT], py[PPT], pz[PPT];
        float ax[PPT], ay[PPT], az[PPT], aw[PPT];
#pragma unroll
        for (int p = 0; p < PPT; ++p) {
            const int n = n0 + threadIdx.x + p * BLOCK;
            px[p] = xb[n]; py[p] = xb[N_ + n]; pz[p] = xb[2 * N_ + n];
            ax[p] = 0.f; ay[p] = 0.f; az[p] = 0.f; aw[p] = 0.f;
        }

        // ---- main loop (R5-measured codegen) ----
#pragma unroll 2
        for (int t = 0; t < CHUNK; ++t) {
            const float4 a = As[t];   // broadcast ds_read_b128
            const float4 f = Fs[t];
#pragma unroll
            for (int p = 0; p < PPT; ++p) {
                float e = fmaf(pz[p], a.z, a.w);
                e = fmaf(py[p], a.y, e);
                e = fmaf(px[p], a.x, e);
                const float k = __builtin_amdgcn_exp2f(e);
                ax[p] = fmaf(k, f.x, ax[p]);
                ay[p] = fmaf(k, f.y, ay[p]);
                az[p] = fmaf(k, f.z, az[p]);
                aw[p] += k;
            }
        }

        // ---- write partials (coalesced float4, idempotent per rep) ----
#pragma unroll
        for (int p = 0; p < PPT; ++p) {
            const int g = b * N_ + n0 + threadIdx.x + p * BLOCK;
            pp[(size_t)sc * BN + g] = make_float4(ax[p], ay[p], az[p], aw[p]);
        }
        __syncthreads();   // protect As/Fs before next rep restages
    }
}

__global__ __launch_bounds__(BLOCK) void uf2_combine(
    const float4* __restrict__ part, float* __restrict__ out, int SC)
{
    const int g = blockIdx.x * BLOCK + threadIdx.x;   // 0..BN-1
    float4 s0 = make_float4(0.f, 0.f, 0.f, 0.f);
    float4 s1 = s0, s2 = s0, s3 = s0;
    int c = 0;
    for (; c + 4 <= SC; c += 4) {
        const float4 p0 = part[(size_t)(c + 0) * BN + g];
        const float4 p1 = part[(size_t)(c + 1) * BN + g];
        const float4 p2 = part[(size_t)(c + 2) * BN + g];
        const float4 p3 = part[(size_t)(c + 3) * BN + g];
        s0.x += p0.x; s0.y += p0.y; s0.z += p0.z; s0.w += p0.w;
        s1.x += p1.x; s1.y += p1.y; s1.z += p1.z; s1.w += p1.w;
        s2.x += p2.x; s2.y += p2.y; s2.z += p2.z; s2.w += p2.w;
        s3.x += p3.x; s3.y += p3.y; s3.z += p3.z; s3.w += p3.w;
    }
    for (; c < SC; ++c) {
        const float4 p = part[(size_t)c * BN + g];
        s0.x += p.x; s0.y += p.y; s0.z += p.z; s0.w += p.w;
    }
    const float sx = (s0.x + s1.x) + (s2.x + s3.x);
    const float sy = (s0.y + s1.y) + (s2.y + s3.y);
    const float sz = (s0.z + s1.z) + (s2.z + s3.z);
    const float sw = (s0.w + s1.w) + (s2.w + s3.w);
    const float inv = 1.0f / sw;
    const int b = g >> 13;            // /8192
    const int n = g & (N_ - 1);
    float* ob = out + b * 3 * N_;
    ob[n]          = sx * inv;
    ob[N_ + n]     = sy * inv;
    ob[2 * N_ + n] = sz * inv;
}

// Fallback (ws too small): single kernel, full S staged in LDS, direct out.
__global__ __launch_bounds__(BLOCK, 1) void uf2_fused(
    const float* __restrict__ xyz,
    const float* __restrict__ sxyz,
    const float* __restrict__ sflow,
    const int* __restrict__ resol,
    float* __restrict__ out)
{
    constexpr int FPPT = 4;
    constexpr int PTS = BLOCK * FPPT;
    __shared__ float4 As[S_];
    __shared__ float4 Fs[S_];

    const int nb = blockIdx.x;
    const int b  = nb / (N_ / PTS);
    const int n0 = (nb % (N_ / PTS)) * PTS;

    const float r = (float)resol[0];
    const float inv_r2 = 1.0f / (r * r);
    const float c2 = 2.0f * inv_r2 * LOG2E;
    const float cy = -inv_r2 * LOG2E;

    const float* yb = sxyz  + b * 3 * S_;
    const float* fb = sflow + b * 3 * S_;
    for (int t = threadIdx.x; t < S_; t += BLOCK) {
        const float yx = yb[t], yy = yb[S_ + t], yz = yb[2 * S_ + t];
        const float fx = fb[t], fy = fb[S_ + t], fz = fb[2 * S_ + t];
        As[t] = make_float4(c2 * yx, c2 * yy, c2 * yz,
                            cy * (yx * yx + yy * yy + yz * yz));
        Fs[t] = make_float4(fx, fy, fz, 0.0f);
    }
    __syncthreads();

    const float* xb = xyz + b * 3 * N_;
    float px[FPPT], py[FPPT], pz[FPPT];
    float4 acc[FPPT];
#pragma unroll
    for (int p = 0; p < FPPT; ++p) {
        const int n = n0 + threadIdx.x + p * BLOCK;
        px[p] = xb[n]; py[p] = xb[N_ + n]; pz[p] = xb[2 * N_ + n];
        acc[p] = make_float4(0.f, 0.f, 0.f, 0.f);
    }
#pragma unroll 4
    for (int t = 0; t < S_; ++t) {
        const float4 a = As[t];
        const float4 f = Fs[t];
#pragma unroll
        for (int p = 0; p < FPPT; ++p) {
            float e = fmaf(pz[p], a.z, a.w);
            e = fmaf(py[p], a.y, e);
            e = fmaf(px[p], a.x, e);
            const float k = __builtin_amdgcn_exp2f(e);
            acc[p].x = fmaf(k, f.x, acc[p].x);
            acc[p].y = fmaf(k, f.y, acc[p].y);
            acc[p].z = fmaf(k, f.z, acc[p].z);
            acc[p].w += k;
        }
    }
#pragma unroll
    for (int p = 0; p < FPPT; ++p) {
        const int n = n0 + threadIdx.x + p * BLOCK;
        const float inv = 1.0f / acc[p].w;
        float* ob = out + b * 3 * N_;
        ob[n]          = acc[p].x * inv;
        ob[N_ + n]     = acc[p].y * inv;
        ob[2 * N_ + n] = acc[p].z * inv;
    }
}

extern "C" void kernel_launch(void* const* d_in, const int* in_sizes, int n_in,
                              void* d_out, int out_size, void* d_ws, size_t ws_size,
                              hipStream_t stream)
{
    const float* xyz   = (const float*)d_in[0];
    const float* sxyz  = (const float*)d_in[1];
    const float* sflow = (const float*)d_in[2];
    const int*   resol = (const int*)d_in[3];
    float* out = (float*)d_out;
    float4* part = (float4*)d_ws;

    const size_t per_chunk = (size_t)BN * sizeof(float4);   // 512 KB
    int SC = 16;
    while (SC > 1 && (size_t)SC * per_chunk > ws_size) SC >>= 1;

    if ((size_t)SC * per_chunk > ws_size) {
        uf2_fused<<<dim3(BN / 1024), dim3(BLOCK), 0, stream>>>(
            xyz, sxyz, sflow, resol, out);
        return;
    }

    dim3 grid(NB * SC), blk(BLOCK);
    switch (SC) {
        case 16: uf2_main<S_ / 16><<<grid, blk, 0, stream>>>(xyz, sxyz, sflow, resol, part); break;
        case 8:  uf2_main<S_ / 8 ><<<grid, blk, 0, stream>>>(xyz, sxyz, sflow, resol, part); break;
        case 4:  uf2_main<S_ / 4 ><<<grid, blk, 0, stream>>>(xyz, sxyz, sflow, resol, part); break;
        case 2:  uf2_main<S_ / 2 ><<<grid, blk, 0, stream>>>(xyz, sxyz, sflow, resol, part); break;
        default: uf2_main<S_     ><<<grid, blk, 0, stream>>>(xyz, sxyz, sflow, resol, part); break;
    }
    uf2_combine<<<dim3(BN / BLOCK), dim3(BLOCK), 0, stream>>>(part, out, SC);
}